// Round 3
// baseline (107.782 us; speedup 1.0000x reference)
//
#include <hip/hip_runtime.h>
#include <math.h>

#define N 8
#define C 128
#define L 1024
#define K 100
#define TEMP 0.5f
#define EPS 1e-8f

typedef _Float16 h2 __attribute__((ext_vector_type(2)));
union U4 { uint4 u; h2 h[4]; };   // 16 B = 8 halves = 4 half2

__device__ __forceinline__ float fd2(h2 a, h2 b, float acc) {
#if __has_builtin(__builtin_amdgcn_fdot2)
    return __builtin_amdgcn_fdot2(a, b, acc, false);
#else
    return acc + (float)a[0] * (float)b[0] + (float)a[1] * (float)b[1];
#endif
}

// Transpose+convert: dst[n][l][ch] = (fp16) src[(n*C+ch)*slen + off + l]
// blockIdx.z: 0-7 -> z slab n, 8-15 -> c slab n (skip col 0)
__global__ void __launch_bounds__(512)
transpose_both(const float* __restrict__ z, const float* __restrict__ c,
               _Float16* __restrict__ z_h, _Float16* __restrict__ c_h) {
    __shared__ float tile[64][65];
    const int which = blockIdx.z >> 3;
    const int n = blockIdx.z & 7;
    const float* src = which ? c : z;
    _Float16* dst = which ? c_h : z_h;
    const int slen = which ? (L + 1) : L;
    const int off = which;
    const int l0 = blockIdx.x * 64;
    const int c0 = blockIdx.y * 64;
    const int tx = threadIdx.x;   // 0..63
    const int ty = threadIdx.y;   // 0..7
#pragma unroll
    for (int i = 0; i < 8; i++) {
        int ch = c0 + ty + i * 8;
        tile[ty + i * 8][tx] = src[((size_t)(n * C + ch)) * slen + off + l0 + tx];
    }
    __syncthreads();
#pragma unroll
    for (int i = 0; i < 8; i++) {
        int l = l0 + ty + i * 8;
        dst[((size_t)n * L + l) * C + c0 + tx] = (_Float16)tile[tx][ty + i * 8];
    }
}

// One wave per (n,t). 8 lanes per target, 8 targets per wave-iteration.
__global__ void __launch_bounds__(256)
ssl_main(const _Float16* __restrict__ zh, const _Float16* __restrict__ ch,
         const int* __restrict__ neg_inds,
         const float* __restrict__ z_orig, const float* __restrict__ c_orig,
         float* __restrict__ out) {
    const int tid  = threadIdx.x;
    const int lane = tid & 63;
    const int g    = lane >> 3;       // target group 0..7
    const int s    = lane & 7;        // 32B slice within row
    const int nt   = blockIdx.x * 4 + (tid >> 6);
    const int n    = nt >> 10;
    const int t    = nt & (L - 1);

    // context fragment: halves [s*16, s*16+16)
    const uint4* crow = (const uint4*)(ch + (size_t)nt * C);
    U4 ca, cb;
    ca.u = crow[2 * s];
    cb.u = crow[2 * s + 1];
    float cn = 0.f;
#pragma unroll
    for (int j = 0; j < 4; j++) { cn = fd2(ca.h[j], ca.h[j], cn); cn = fd2(cb.h[j], cb.h[j], cn); }
#pragma unroll
    for (int o = 1; o < 8; o <<= 1) cn += __shfl_xor(cn, o);
    const float cd = fmaxf(sqrtf(cn), EPS) * TEMP;

    const int* ni = neg_inds + (size_t)nt * K;
    const _Float16* zbase = zh + (((size_t)n) << 10) * C;

    int idx_c = (g == 0) ? t : ni[g - 1];    // iter 0: kk = g
    int idx_n = ni[7 + g];                   // iter 1: kk = 8+g
    U4 za, zb;
    {
        const uint4* zr = (const uint4*)(zbase + (size_t)idx_c * C);
        za.u = zr[2 * s]; zb.u = zr[2 * s + 1];
    }
    int idx_n2 = 0;

    for (int i = 0; i < 13; i++) {
        U4 zan, zbn;
        zan.u = za.u; zbn.u = zb.u;
        if (i < 12) {                        // prefetch row for iter i+1
            const uint4* zr = (const uint4*)(zbase + (size_t)idx_n * C);
            zan.u = zr[2 * s]; zbn.u = zr[2 * s + 1];
        }
        if (i < 11) {                        // prefetch index for iter i+2
            int kk2 = (i + 2) * 8 + g;
            idx_n2 = (kk2 <= K) ? ni[kk2 - 1] : 0;
        }

        float dot = 0.f, tn = 0.f;
#pragma unroll
        for (int j = 0; j < 4; j++) { dot = fd2(ca.h[j], za.h[j], dot); tn = fd2(za.h[j], za.h[j], tn); }
#pragma unroll
        for (int j = 0; j < 4; j++) { dot = fd2(cb.h[j], zb.h[j], dot); tn = fd2(zb.h[j], zb.h[j], tn); }
#pragma unroll
        for (int o = 1; o < 8; o <<= 1) { dot += __shfl_xor(dot, o); tn += __shfl_xor(tn, o); }

        int kk = i * 8 + g;
        if (s == 0 && kk <= K) {
            float logit = dot / (cd * fmaxf(sqrtf(tn), EPS));
            if (kk > 0) {
                float ds = cn - 2.f * dot + tn;   // ||c-z||^2 in fp16 space; ==0 iff bitwise equal
                if (ds < 1e-3f * cn) {            // near-equal: exact fp32 recheck (never on random data)
                    bool eq = true;
                    for (int q = 0; q < C; q++) {
                        float cv = c_orig[((size_t)(n * C + q)) * (L + 1) + t + 1];
                        float zv = z_orig[((size_t)(n * C + q)) * L + idx_c];
                        eq = eq && (cv == zv);
                    }
                    if (eq) logit = -INFINITY;
                }
            }
            out[(size_t)nt * (K + 1) + kk] = logit;
        }

        za.u = zan.u; zb.u = zbn.u;
        idx_c = idx_n; idx_n = idx_n2;
    }
}

extern "C" void kernel_launch(void* const* d_in, const int* in_sizes, int n_in,
                              void* d_out, int out_size, void* d_ws, size_t ws_size,
                              hipStream_t stream) {
    const float* z   = (const float*)d_in[0];   // (N, C, L)
    const float* c   = (const float*)d_in[1];   // (N, C, L+1)
    const int*   neg = (const int*)d_in[2];     // (N, L, K)
    float* out = (float*)d_out;                 // (N*L, K+1)

    _Float16* z_h = (_Float16*)d_ws;            // (N, L, C) fp16, 2 MB
    _Float16* c_h = z_h + (size_t)N * L * C;    // (N, L, C) fp16, 2 MB

    transpose_both<<<dim3(L / 64, C / 64, 16), dim3(64, 8), 0, stream>>>(z, c, z_h, c_h);
    ssl_main<<<dim3((N * L) / 4), 256, 0, stream>>>(z_h, c_h, neg, z, c, out);
}

// Round 4
// 81.284 us; speedup vs baseline: 1.3260x; 1.3260x over previous
//
#include <hip/hip_runtime.h>
#include <math.h>

#define N 8
#define C 128
#define L 1024
#define K 100
#define TEMP 0.5f
#define EPS 1e-8f
#define NT (N * L)

typedef _Float16 h2 __attribute__((ext_vector_type(2)));
union U4 { uint4 u; h2 h[4]; };   // 16 B = 4 half2

__device__ __forceinline__ float fd2(h2 a, h2 b, float acc) {
#if __has_builtin(__builtin_amdgcn_fdot2)
    return __builtin_amdgcn_fdot2(a, b, acc, false);
#else
    return acc + (float)a[0] * (float)b[0] + (float)a[1] * (float)b[1];
#endif
}

// quad_perm DPP cross-lane add: xor1 = [1,0,3,2] = 0xB1, xor2 = [2,3,0,1] = 0x4E
#if __has_builtin(__builtin_amdgcn_mov_dpp)
#define DPP_ADD(x, ctrl) ((x) + __int_as_float(__builtin_amdgcn_mov_dpp(__float_as_int(x), (ctrl), 0xF, 0xF, true)))
#else
#define DPP_ADD(x, ctrl) ((x) + __shfl_xor((x), ((ctrl) == 0xB1 ? 1 : 2)))
#endif

// Transpose+fp16-convert+fp32-row-norm-partials.
// dst[n][l][ch] = (fp16) src[(n*C+ch)*slen + off + l]
// pdst[(n*L+l)*2 + c0/64] = sum over this block's 64 channels of src^2 (fp32)
// blockIdx.z: 0-7 -> z slab n, 8-15 -> c slab n (skip col 0)
__global__ void __launch_bounds__(512)
transpose_both(const float* __restrict__ z, const float* __restrict__ c,
               _Float16* __restrict__ z_h, _Float16* __restrict__ c_h,
               float* __restrict__ zp, float* __restrict__ cp) {
    __shared__ float tile[64][65];
    __shared__ float part[8][64];
    const int which = blockIdx.z >> 3;
    const int n = blockIdx.z & 7;
    const float* src = which ? c : z;
    _Float16* dst = which ? c_h : z_h;
    float* pdst = which ? cp : zp;
    const int slen = which ? (L + 1) : L;
    const int off = which;
    const int l0 = blockIdx.x * 64;
    const int c0 = blockIdx.y * 64;
    const int tx = threadIdx.x;   // 0..63
    const int ty = threadIdx.y;   // 0..7
#pragma unroll
    for (int i = 0; i < 8; i++) {
        int chn = c0 + ty + i * 8;
        tile[ty + i * 8][tx] = src[((size_t)(n * C + chn)) * slen + off + l0 + tx];
    }
    __syncthreads();
#pragma unroll
    for (int i = 0; i < 8; i++) {
        int l = l0 + ty + i * 8;
        dst[((size_t)n * L + l) * C + c0 + tx] = (_Float16)tile[tx][ty + i * 8];
    }
    // partial row norms (fp32, over this block's 64 channels) for l = l0+tx
    float p = 0.f;
#pragma unroll
    for (int i = 0; i < 8; i++) { float v = tile[ty * 8 + i][tx]; p += v * v; }
    part[ty][tx] = p;
    __syncthreads();
    if (ty == 0) {
        float sm = 0.f;
#pragma unroll
        for (int i = 0; i < 8; i++) sm += part[i][tx];
        pdst[(((size_t)n << 10) + l0 + tx) * 2 + (c0 >> 6)] = sm;
    }
}

// One wave per (n,t). 4 lanes (one quad) per target, 16 targets per wave-iter.
// Lane s of quad g loads interleaved 16B slices {s,s+4,s+8,s+12} of its row.
// Dot reduced with 2 DPP quad_perm adds — no LDS ops anywhere in this kernel.
__global__ void __launch_bounds__(256)
ssl_main(const _Float16* __restrict__ zh, const _Float16* __restrict__ chh,
         const int* __restrict__ neg_inds,
         const float* __restrict__ zp, const float* __restrict__ cp,
         const float* __restrict__ z_orig, const float* __restrict__ c_orig,
         float* __restrict__ out) {
    const int tid  = threadIdx.x;
    const int lane = tid & 63;
    const int g    = lane >> 2;       // quad (target group) 0..15
    const int s    = lane & 3;        // slice within row
    const int nt   = blockIdx.x * 4 + (tid >> 6);
    const int n    = nt >> 10;
    const int t    = nt & (L - 1);

    const uint4* crow = (const uint4*)(chh + (size_t)nt * C);
    U4 cf[4];
#pragma unroll
    for (int j = 0; j < 4; j++) cf[j].u = crow[s + 4 * j];

    const float2 cpv = ((const float2*)cp)[nt];
    const float cn = cpv.x + cpv.y;                 // fp32 ||c||^2
    const float cd = fmaxf(sqrtf(cn), EPS) * TEMP;

    const int* ni = neg_inds + (size_t)nt * K;
    const _Float16* zbase = zh + (((size_t)n) << 10) * C;
    const float2* zp2 = (const float2*)zp + ((size_t)n << 10);

    int idx_cur = (g == 0) ? t : ni[g - 1];         // iter 0: kk = g
    int idx_nxt = ni[15 + g];                       // iter 1: kk = 16+g
    U4 zc[4];
    {
        const uint4* zr = (const uint4*)(zbase + (size_t)idx_cur * C);
#pragma unroll
        for (int j = 0; j < 4; j++) zc[j].u = zr[s + 4 * j];
    }
    float2 tv0 = zp2[idx_cur];
    float tn_cur = tv0.x + tv0.y;

#pragma unroll
    for (int i = 0; i < 7; i++) {
        U4 znx[4];
        float tn_nxt = 0.f;
        int idx_n2 = 0;
        if (i < 6) {                                 // prefetch row+norm for iter i+1
            const uint4* zr = (const uint4*)(zbase + (size_t)idx_nxt * C);
#pragma unroll
            for (int j = 0; j < 4; j++) znx[j].u = zr[s + 4 * j];
            float2 tv = zp2[idx_nxt];
            tn_nxt = tv.x + tv.y;
        }
        if (i < 5) {                                 // prefetch index for iter i+2
            int kk2 = (i + 2) * 16 + g;
            idx_n2 = (kk2 <= K) ? ni[kk2 - 1] : 0;
        }

        float d0 = 0.f, d1 = 0.f;                    // 2 accumulators for ILP
#pragma unroll
        for (int j = 0; j < 4; j++) {
            d0 = fd2(cf[j].h[0], zc[j].h[0], d0);
            d1 = fd2(cf[j].h[1], zc[j].h[1], d1);
            d0 = fd2(cf[j].h[2], zc[j].h[2], d0);
            d1 = fd2(cf[j].h[3], zc[j].h[3], d1);
        }
        float dot = d0 + d1;
        dot = DPP_ADD(dot, 0xB1);                    // + lane^1
        dot = DPP_ADD(dot, 0x4E);                    // + lane^2

        int kk = i * 16 + g;
        if (s == 0 && kk <= K) {
            float logit = dot / (cd * fmaxf(sqrtf(tn_cur), EPS));
            if (kk > 0) {
                float ds = cn - 2.f * dot + tn_cur;  // ~0 iff c == z_idx; ~2cn otherwise
                if (ds < 0.05f * cn) {               // rare: exact fp32 recheck
                    bool eq = true;
                    for (int q = 0; q < C; q++) {
                        float cv = c_orig[((size_t)(n * C + q)) * (L + 1) + t + 1];
                        float zv = z_orig[((size_t)(n * C + q)) * L + idx_cur];
                        eq = eq && (cv == zv);
                    }
                    if (eq) logit = -INFINITY;
                }
            }
            out[(size_t)nt * (K + 1) + kk] = logit;
        }

#pragma unroll
        for (int j = 0; j < 4; j++) zc[j].u = znx[j].u;
        idx_cur = idx_nxt;
        idx_nxt = idx_n2;
        tn_cur = tn_nxt;
    }
}

extern "C" void kernel_launch(void* const* d_in, const int* in_sizes, int n_in,
                              void* d_out, int out_size, void* d_ws, size_t ws_size,
                              hipStream_t stream) {
    const float* z   = (const float*)d_in[0];   // (N, C, L)
    const float* c   = (const float*)d_in[1];   // (N, C, L+1)
    const int*   neg = (const int*)d_in[2];     // (N, L, K)
    float* out = (float*)d_out;                 // (N*L, K+1)

    _Float16* z_h = (_Float16*)d_ws;            // (N, L, C) fp16, 2 MB
    _Float16* c_h = z_h + (size_t)NT * C;       // (N, L, C) fp16, 2 MB
    float* zp = (float*)(c_h + (size_t)NT * C); // (N*L, 2) fp32 norm partials, 64 KB
    float* cp = zp + (size_t)NT * 2;            // (N*L, 2) fp32 norm partials, 64 KB

    transpose_both<<<dim3(L / 64, C / 64, 16), dim3(64, 8), 0, stream>>>(z, c, z_h, c_h, zp, cp);
    ssl_main<<<dim3(NT / 4), 256, 0, stream>>>(z_h, c_h, neg, zp, cp, z, c, out);
}

// Round 5
// 79.786 us; speedup vs baseline: 1.3509x; 1.0188x over previous
//
#include <hip/hip_runtime.h>
#include <math.h>

#define N 8
#define C 128
#define L 1024
#define K 100
#define TEMP 0.5f
#define EPS 1e-8f
#define NT (N * L)

typedef _Float16 h2 __attribute__((ext_vector_type(2)));
union U4 { uint4 u; h2 h[4]; };   // 16 B = 4 half2

__device__ __forceinline__ float fd2(h2 a, h2 b, float acc) {
#if __has_builtin(__builtin_amdgcn_fdot2)
    return __builtin_amdgcn_fdot2(a, b, acc, false);
#else
    return acc + (float)a[0] * (float)b[0] + (float)a[1] * (float)b[1];
#endif
}

// quad_perm DPP cross-lane add: xor1 = [1,0,3,2] = 0xB1, xor2 = [2,3,0,1] = 0x4E
#if __has_builtin(__builtin_amdgcn_mov_dpp)
#define DPP_ADD(x, ctrl) ((x) + __int_as_float(__builtin_amdgcn_mov_dpp(__float_as_int(x), (ctrl), 0xF, 0xF, true)))
#else
#define DPP_ADD(x, ctrl) ((x) + __shfl_xor((x), ((ctrl) == 0xB1 ? 1 : 2)))
#endif

// Transpose+fp16-convert+fp32-row-norm-partials.
// dst[n][l][ch] = (fp16) src[(n*C+ch)*slen + off + l]
// pdst[(n*L+l)*2 + c0/64] = partial sum of src^2 over this block's 64 channels
// blockIdx.z: 0-7 -> z slab n, 8-15 -> c slab n (skip col 0)
__global__ void __launch_bounds__(512)
transpose_both(const float* __restrict__ z, const float* __restrict__ c,
               _Float16* __restrict__ z_h, _Float16* __restrict__ c_h,
               float* __restrict__ zp, float* __restrict__ cp) {
    __shared__ float tile[64][65];
    __shared__ float part[8][64];
    const int which = blockIdx.z >> 3;
    const int n = blockIdx.z & 7;
    const float* src = which ? c : z;
    _Float16* dst = which ? c_h : z_h;
    float* pdst = which ? cp : zp;
    const int slen = which ? (L + 1) : L;
    const int off = which;
    const int l0 = blockIdx.x * 64;
    const int c0 = blockIdx.y * 64;
    const int tx = threadIdx.x;   // 0..63
    const int ty = threadIdx.y;   // 0..7
#pragma unroll
    for (int i = 0; i < 8; i++) {
        int chn = c0 + ty + i * 8;
        tile[ty + i * 8][tx] = src[((size_t)(n * C + chn)) * slen + off + l0 + tx];
    }
    __syncthreads();
#pragma unroll
    for (int i = 0; i < 8; i++) {
        int l = l0 + ty + i * 8;
        dst[((size_t)n * L + l) * C + c0 + tx] = (_Float16)tile[tx][ty + i * 8];
    }
    float p = 0.f;
#pragma unroll
    for (int i = 0; i < 8; i++) { float v = tile[ty * 8 + i][tx]; p += v * v; }
    part[ty][tx] = p;
    __syncthreads();
    if (ty == 0) {
        float sm = 0.f;
#pragma unroll
        for (int i = 0; i < 8; i++) sm += part[i][tx];
        pdst[(((size_t)n << 10) + l0 + tx) * 2 + (c0 >> 6)] = sm;
    }
}

// One wave per (n,t). 4 lanes (one quad) per target, 16 targets per wave-iter,
// 7 fully-unrolled iters. All indices + norms loaded upfront; rows issued
// 2 iterations ahead (3 live row buffers). No LDS ops, no divides.
__global__ void __launch_bounds__(256)
ssl_main(const _Float16* __restrict__ zh, const _Float16* __restrict__ chh,
         const int* __restrict__ neg_inds,
         const float* __restrict__ zp, const float* __restrict__ cp,
         const float* __restrict__ z_orig, const float* __restrict__ c_orig,
         float* __restrict__ out) {
    const int tid  = threadIdx.x;
    const int lane = tid & 63;
    const int g    = lane >> 2;       // quad (target group) 0..15
    const int s    = lane & 3;        // slice within row
    const int nt   = blockIdx.x * 4 + (tid >> 6);
    const int n    = nt >> 10;
    const int t    = nt & (L - 1);

    const uint4* crow = (const uint4*)(chh + (size_t)nt * C);
    U4 cf[4];
#pragma unroll
    for (int j = 0; j < 4; j++) cf[j].u = crow[s + 4 * j];

    const float2 cpv = ((const float2*)cp)[nt];
    const float cn = cpv.x + cpv.y;                 // fp32 ||c||^2
    const float rs_c = 2.0f * rsqrtf(fmaxf(cn, EPS * EPS));   // 1/(TEMP*sqrt(cn))

    const int* ni = neg_inds + (size_t)nt * K;
    const _Float16* zbase = zh + (((size_t)n) << 10) * C;
    const float2* zp2 = (const float2*)zp + ((size_t)n << 10);

    // all per-lane indices upfront (kills per-iter idx->row chain)
    int idxs[7];
#pragma unroll
    for (int i = 0; i < 7; i++) {
        int kk = i * 16 + g;
        idxs[i] = (kk == 0) ? t : ((kk <= K) ? ni[kk - 1] : 0);
    }
    // all row norms upfront (7 independent 8B loads)
    float tns[7];
#pragma unroll
    for (int i = 0; i < 7; i++) { float2 tv = zp2[idxs[i]]; tns[i] = tv.x + tv.y; }

    U4 rows[7][4];
#pragma unroll
    for (int p = 0; p < 2; p++) {                   // preload iters 0,1
        const uint4* zr = (const uint4*)(zbase + (size_t)idxs[p] * C);
#pragma unroll
        for (int j = 0; j < 4; j++) rows[p][j].u = zr[s + 4 * j];
    }

#pragma unroll
    for (int i = 0; i < 7; i++) {
        if (i + 2 < 7) {                             // issue rows for iter i+2
            const uint4* zr = (const uint4*)(zbase + (size_t)idxs[i + 2] * C);
#pragma unroll
            for (int j = 0; j < 4; j++) rows[i + 2][j].u = zr[s + 4 * j];
        }

        float d0 = 0.f, d1 = 0.f;
#pragma unroll
        for (int j = 0; j < 4; j++) {
            d0 = fd2(cf[j].h[0], rows[i][j].h[0], d0);
            d1 = fd2(cf[j].h[1], rows[i][j].h[1], d1);
            d0 = fd2(cf[j].h[2], rows[i][j].h[2], d0);
            d1 = fd2(cf[j].h[3], rows[i][j].h[3], d1);
        }
        float dot = d0 + d1;
        dot = DPP_ADD(dot, 0xB1);                    // + lane^1
        dot = DPP_ADD(dot, 0x4E);                    // + lane^2

        int kk = i * 16 + g;
        if (s == 0 && kk <= K) {
            float logit = dot * rs_c * rsqrtf(fmaxf(tns[i], EPS * EPS));
            if (kk > 0) {
                float ds = cn - 2.f * dot + tns[i];  // ~0 iff c == z_idx; ~2cn otherwise
                if (ds < 0.05f * cn) {               // rare: exact fp32 recheck
                    bool eq = true;
                    for (int q = 0; q < C; q++) {
                        float cv = c_orig[((size_t)(n * C + q)) * (L + 1) + t + 1];
                        float zv = z_orig[((size_t)(n * C + q)) * L + idxs[i]];
                        eq = eq && (cv == zv);
                    }
                    if (eq) logit = -INFINITY;
                }
            }
            out[(size_t)nt * (K + 1) + kk] = logit;
        }
    }
}

extern "C" void kernel_launch(void* const* d_in, const int* in_sizes, int n_in,
                              void* d_out, int out_size, void* d_ws, size_t ws_size,
                              hipStream_t stream) {
    const float* z   = (const float*)d_in[0];   // (N, C, L)
    const float* c   = (const float*)d_in[1];   // (N, C, L+1)
    const int*   neg = (const int*)d_in[2];     // (N, L, K)
    float* out = (float*)d_out;                 // (N*L, K+1)

    _Float16* z_h = (_Float16*)d_ws;            // (N, L, C) fp16, 2 MB
    _Float16* c_h = z_h + (size_t)NT * C;       // (N, L, C) fp16, 2 MB
    float* zp = (float*)(c_h + (size_t)NT * C); // (N*L, 2) fp32 norm partials
    float* cp = zp + (size_t)NT * 2;            // (N*L, 2) fp32 norm partials

    transpose_both<<<dim3(L / 64, C / 64, 16), dim3(64, 8), 0, stream>>>(z, c, z_h, c_h, zp, cp);
    ssl_main<<<dim3(NT / 4), 256, 0, stream>>>(z_h, c_h, neg, zp, cp, z, c, out);
}